// Round 8
// baseline (493.215 us; speedup 1.0000x reference)
//
#include <hip/hip_runtime.h>
#include <hip/hip_bf16.h>
#include <stdint.h>

// QuantizedLinear: out_f32[512,16384] = x_f32[512,4096] @ (qw_i32 * scales)^T + bias
// dtypes (verified round 3): x fp32, qw int32, scales fp32, bias fp32, out fp32.
//
// Round-15: two mechanism fixes.
// (1) gemm: r13/r14 loaded A INSIDE the consuming iteration -> in-order vmcnt
//     forces the just-issued B-stage (HBM ~900cy) + A L2 latency onto the
//     critical path EVERY iter. Fix: A-prefetch one iter ahead (named aA/aB
//     reg dbuf, hand 2x unroll); iteration = issue stage(kb+1)+A(kb+1),
//     compute(kb) with ZERO vmem waits, __syncthreads (drain covered by
//     ~3.1k cyc compute). True m97 semantics.
// (2) pack_w v3: r14's per-thread-contiguous 128B still made each dwordx4
//     instruction touch 64 lines (lane stride 128B). v3 uses wave-linear
//     chunks: instruction i reads a CONTIGUOUS 4KB (8 lines/inst), scales
//     cached in LDS, transpose via lw[64][132] (write 2-way, read <=4-way),
//     coalesced 16B/lane stores. wb bit-identical to r13/r14.
// Floors: pack_w ~61us (384MB stream), gemm ~33us MFMA / ~41us LDS-pipe.
// Predict total 490 -> ~385-420.

#define MM 512
#define NN 16384
#define KK 4096
#define BN 64
#define BK 128
#define NKB (KK / BK)    // 32
#define NSLAB (NN / BN)  // 256

typedef __bf16 bf16x8 __attribute__((ext_vector_type(8)));
typedef float floatx4 __attribute__((ext_vector_type(4)));

__device__ __forceinline__ unsigned int pk_bf16_rtn(float lo, float hi) {
    __hip_bfloat162 h = __float22bfloat162_rn(float2{lo, hi});
    return *reinterpret_cast<unsigned int*>(&h);
}

// async global->LDS, 16B per lane; LDS dest = wave-uniform base + lane*16 (m104).
__device__ __forceinline__ void gload16(const void* g, void* l) {
    __builtin_amdgcn_global_load_lds(
        (const __attribute__((address_space(1))) void*)g,
        (__attribute__((address_space(3))) void*)l, 16, 0, 0);
}

// ---- prepass 1: x fp32 -> bf16, packed in MFMA A-fragment order ----
// xp element index: (((kb*4 + ks)*32 + mt)*64 + lane)*8,
//   holding x[mt*16 + (lane&15)][kb*128 + ks*32 + (lane>>4)*8 .. +8]
__global__ __launch_bounds__(256) void pack_x(const float* __restrict__ x,
                                              unsigned short* __restrict__ xp) {
    const int t    = blockIdx.x * 256 + threadIdx.x;   // 0..262143
    const int lane = t & 63;
    const int mt   = (t >> 6) & 31;
    const int ks   = (t >> 11) & 3;
    const int kb   = t >> 13;
    const int m    = mt * 16 + (lane & 15);
    const int k    = kb * 128 + ks * 32 + (lane >> 4) * 8;
    const float* px = x + (size_t)m * KK + k;
    const float4 a = *(const float4*)px;
    const float4 b = *(const float4*)(px + 4);
    uint4 o;
    o.x = pk_bf16_rtn(a.x, a.y);
    o.y = pk_bf16_rtn(a.z, a.w);
    o.z = pk_bf16_rtn(b.x, b.y);
    o.w = pk_bf16_rtn(b.z, b.w);
    *(uint4*)(xp + (size_t)t * 8) = o;   // fully coalesced 16B/thread
}

// ---- prepass 2 (v3): dequant qw -> wb, instruction-coalesced both sides ----
// One 256-thr block per (slab,kb) tile (8192 blocks). Tile = 64 rows x 128 k.
// Phase 0: cache the tile's 128 scales in LDS (ls[r*2+blk]).
// Phase 1: 2048 input chunks of 16B (4 int32). Thread u, inst i: chunk
//   c = i*256+u -> wave covers 64 consecutive chunks = 2 contiguous 512B row
//   segments (8 lines/inst, fully coalesced). row r=c>>5, kk=(c&31)*4.
//   Dequant 4 vals with ls[r*2 + ((c&31)>>4)] -> ds_write_b64 lw[r][kk].
// Phase 2: 1024 output chunks; f=c>>6 (=ks*4+j), l=c&63; read 16B
//   lw[j*16+(l&15)][ks*32+(l>>4)*8] (<=4-way aliasing, cheap) -> wt+c*8,
//   lanes consecutive => coalesced 4KB/inst stores. wb bit-identical to r13.
__global__ __launch_bounds__(256) void pack_w(const int* __restrict__ qw,
                                              const float* __restrict__ scales,
                                              unsigned short* __restrict__ wb) {
    __shared__ unsigned short lw[64][132];
    __shared__ float ls[128];
    const int tile = blockIdx.x;        // 0..8191
    const int slab = tile >> 5;
    const int kb   = tile & 31;
    const int u    = threadIdx.x;       // 0..255

    if (u < 128)
        ls[u] = scales[(size_t)(slab * 64 + (u >> 1)) * 64 + kb * 2 + (u & 1)];
    __syncthreads();

    const int* qbase = qw + (size_t)slab * 64 * KK + kb * 128;
#pragma unroll
    for (int i = 0; i < 8; ++i) {
        const int c  = i * 256 + u;         // 0..2047
        const int r  = c >> 5;              // row 0..63
        const int kk = (c & 31) * 4;        // k-int offset 0..124
        const int4 q = *(const int4*)(qbase + (size_t)r * KK + kk);
        const float s = ls[r * 2 + ((c & 31) >> 4)];
        uint2 o;
        o.x = pk_bf16_rtn((float)q.x * s, (float)q.y * s);
        o.y = pk_bf16_rtn((float)q.z * s, (float)q.w * s);
        *(uint2*)&lw[r][kk] = o;
    }
    __syncthreads();

    unsigned short* wt = wb + (size_t)tile * 8192;   // 1024 chunks * 8 shorts
#pragma unroll
    for (int hc = 0; hc < 4; ++hc) {
        const int c  = hc * 256 + u;
        const int f  = c >> 6;
        const int l  = c & 63;
        const int ks = f >> 2;
        const int j  = f & 3;
        const uint4 v = *(const uint4*)&lw[j * 16 + (l & 15)][ks * 32 + (l >> 4) * 8];
        *(uint4*)(wt + (size_t)c * 8) = v;
    }
}

// ---- main GEMM: m97 template with A prefetched one iteration ahead ----
#define STAGE_B(KB, BUF)                                                        \
    {                                                                           \
        const unsigned short* src_ = wbase + (size_t)(KB) * 8192 + (size_t)t * 8; \
        gload16(src_,           &sB[BUF][wv * 512]);                            \
        gload16(src_ + 512 * 8, &sB[BUF][4096 + wv * 512]);                     \
    }

#define LOAD_A(DST, KB)                                                         \
    {                                                                           \
        const unsigned short* ap_ =                                             \
            xp + (size_t)(KB) * 65536                                           \
               + (size_t)((h * 16 + wv * 2) * 64 + lane) * 8;                   \
        _Pragma("unroll")                                                       \
        for (int ks = 0; ks < 4; ++ks) {                                        \
            DST[ks][0] = *(const bf16x8*)(ap_ + ks * 16384);                    \
            DST[ks][1] = *(const bf16x8*)(ap_ + ks * 16384 + 512);              \
        }                                                                       \
    }

#define COMPUTE(BUF, A)                                                         \
    {                                                                           \
        const unsigned short* sb_ = sB[BUF];                                    \
        _Pragma("unroll")                                                       \
        for (int ks = 0; ks < 4; ++ks) {                                        \
            _Pragma("unroll")                                                   \
            for (int jj = 0; jj < 4; jj += 2) {                                 \
                bf16x8 b0 = *(const bf16x8*)(sb_ + ((ks * 4 + jj) * 64 + lane) * 8);     \
                bf16x8 b1 = *(const bf16x8*)(sb_ + ((ks * 4 + jj + 1) * 64 + lane) * 8); \
                acc[0][jj]     = __builtin_amdgcn_mfma_f32_16x16x32_bf16(A[ks][0], b0, acc[0][jj], 0, 0, 0);     \
                acc[1][jj]     = __builtin_amdgcn_mfma_f32_16x16x32_bf16(A[ks][1], b0, acc[1][jj], 0, 0, 0);     \
                acc[0][jj + 1] = __builtin_amdgcn_mfma_f32_16x16x32_bf16(A[ks][0], b1, acc[0][jj + 1], 0, 0, 0); \
                acc[1][jj + 1] = __builtin_amdgcn_mfma_f32_16x16x32_bf16(A[ks][1], b1, acc[1][jj + 1], 0, 0, 0); \
            }                                                                   \
        }                                                                       \
    }

__global__ __launch_bounds__(512, 4) void qlin_gemm(
    const unsigned short* __restrict__ xp,      // packed bf16 x (4 MB)
    const unsigned short* __restrict__ wb,      // packed bf16 W (128 MB)
    const float* __restrict__ bias,             // fp32 [16384]
    float* __restrict__ out)                    // fp32 [512,16384]
{
    __shared__ unsigned short sB[2][BN * BK];   // fragment-ordered, 2 x 16 KB

    const int t    = threadIdx.x;     // 0..511
    const int lane = t & 63;
    const int wv   = t >> 6;          // wave 0..7 -> M strip [h*256 + wv*32, +32)
    const int ln   = lane & 15;
    const int quad = lane >> 4;
    const int slab = blockIdx.x & 255;          // column slab
    const int h    = blockIdx.x >> 8;           // M half; slab-pair 256 apart = same XCD
    const int n0   = slab * BN;

    const unsigned short* wbase = wb + (size_t)slab * 32 * 8192;  // this slab's 32 tiles

    floatx4 acc[2][4];
#pragma unroll
    for (int i = 0; i < 2; ++i)
#pragma unroll
        for (int j = 0; j < 4; ++j)
            acc[i][j] = (floatx4)0.0f;

    bf16x8 aA[4][2], aB[4][2];   // A register double-buffer (named; static idx)

    // ---- prologue: tile 0 + A(0) in flight; barrier drains both ----
    STAGE_B(0, 0)
    LOAD_A(aA, 0)
    __syncthreads();

    // ---- main loop, 2 iters per pass (static buffer roles) ----
    for (int kb = 0; kb < NKB; kb += 2) {
        // even iter: consume (buf0, aA); prefetch kb+1 -> (buf1, aB)
        STAGE_B(kb + 1, 1)
        LOAD_A(aB, kb + 1)
        COMPUTE(0, aA)          // zero vmem dependency: aA drained last barrier
        __syncthreads();        // vmcnt(0): stage+A covered by ~3.1k cyc compute

        // odd iter: consume (buf1, aB); prefetch kb+2 -> (buf0, aA)
        if (kb + 2 < NKB) {
            STAGE_B(kb + 2, 0)
            LOAD_A(aA, kb + 2)
        }
        COMPUTE(1, aB)
        if (kb + 2 < NKB) __syncthreads();
    }

    // ---- epilogue: + bias, store fp32 ----
#pragma unroll
    for (int j = 0; j < 4; ++j) {
        const int n = n0 + j * 16 + ln;
        const float bv = bias[n];
#pragma unroll
        for (int i = 0; i < 2; ++i) {
            const int mbase = h * 256 + wv * 32 + i * 16 + quad * 4;
#pragma unroll
            for (int rr = 0; rr < 4; ++rr)
                out[(size_t)(mbase + rr) * NN + n] = acc[i][j][rr] + bv;
        }
    }
}

// ---- fallback (workspace too small; never expected to trigger) ----
__global__ __launch_bounds__(256) void qlin_naive(
    const float* __restrict__ x, const int* __restrict__ qw,
    const float* __restrict__ scales, const float* __restrict__ bias,
    float* __restrict__ out) {
    const int n = blockIdx.x * 256 + threadIdx.x;   // 0..16383
    const int m = blockIdx.y;                       // 0..511
    if (n >= NN || m >= MM) return;
    float accv = 0.0f;
    for (int kb = 0; kb < 64; ++kb) {
        const float s = scales[(size_t)n * 64 + kb];
        float part = 0.0f;
        for (int k = kb * 64; k < kb * 64 + 64; ++k)
            part += x[(size_t)m * KK + k] * (float)qw[(size_t)n * KK + k];
        accv += part * s;
    }
    out[(size_t)m * NN + n] = accv + bias[n];
}

extern "C" void kernel_launch(void* const* d_in, const int* in_sizes, int n_in,
                              void* d_out, int out_size, void* d_ws, size_t ws_size,
                              hipStream_t stream) {
    const float* x    = (const float*)d_in[0];
    const int* qw     = (const int*)d_in[1];
    const float* scl  = (const float*)d_in[2];
    const float* bias = (const float*)d_in[3];
    float* out        = (float*)d_out;

    const size_t XPB = (size_t)MM * KK * sizeof(unsigned short);   // 4 MB
    const size_t WBB = (size_t)NN * KK * sizeof(unsigned short);   // 128 MB

    if (ws_size >= XPB + WBB) {
        unsigned short* xp = (unsigned short*)d_ws;
        unsigned short* wb = (unsigned short*)((char*)d_ws + XPB);
        pack_x<<<dim3(MM * KK / (256 * 8)), dim3(256), 0, stream>>>(x, xp);
        pack_w<<<dim3(NSLAB * 32), dim3(256), 0, stream>>>(qw, scl, wb);
        qlin_gemm<<<dim3(NSLAB * 2), dim3(512), 0, stream>>>(xp, wb, bias, out);
    } else {
        qlin_naive<<<dim3(NN / 256, MM), dim3(256), 0, stream>>>(x, qw, scl, bias, out);
    }
}